// Round 8
// baseline (628.104 us; speedup 1.0000x reference)
//
#include <hip/hip_runtime.h>
#include <cstdint>
#include <cstddef>

// QRNN fused pipeline for MI355X (gfx950).
// B=32, S=2048, D_in=512, D_model=1024, D_mlp=1024, n_cls=128.
//
// ws layout (bytes): U bf16 [2048][1024] @0 (4MB) | Fagg @4MB | Zagg @6MB |
//   h @8MB | q0 @8MB+256K | q1 @8MB+512K | zero page @12MB (4KB) | xb bf16 @16MB (64MB)
//
// qrnn_hyb (round 8): r0's proven 349-us kernel (129-row A stage, h2
// dual-pass: one staged A tile serves x[t]*W AND x[t-1]*V via +-1-row LDS
// read offsets; 24KB staged per 32 MFMA; single xb read per tile) with
// EXACTLY ONE mechanism changed: staging via global_load_lds instead of the
// VGPR round-trip (m151: +35% for this exact swap at 128^2 tiles; kills
// r0's 28 staging VGPRs and its 61% VALUBusy staging cost).
//  - gload_lds writes linearly (base+lane*16); r0's stage_addr rotation is
//    realized by inverse-rotating the SOURCE chunk: q=(p-r-(r>>2))&3
//    (rule #21; pattern verified rounds 1-7). Reads/fragments/epilogue are
//    byte-identical to r0.
//  - ring-2 slots (2 x 24640B = 49280B LDS) -> LDS-capped 3 blocks/CU (same
//    occupancy as r0), launch_bounds(256,3): no register squeeze, no spill.
//  - per stage: vmcnt(0); barrier; stage(s+1 -> other slot); 16 ds_read;
//    2 x [setprio(1); 16 MFMA; setprio(0)]. 16 sync points (not 32).
//  - 129th A row staged by lanes<4 of ALL 4 waves (redundant, same data) so
//    per-wave outstanding-load count stays uniform (7/stage).

typedef __attribute__((ext_vector_type(8))) short short8;
typedef __attribute__((ext_vector_type(4))) float f32x4;

#define ZERO_OFF_E 6291456u    // 12MB / 2 (bf16 elements)
#define XB_OFF_E   8388608u    // 16MB / 2
#define SLOT_STRIDE 24640      // A 8256 + U 16384
#define U_BASE 8256

__device__ __forceinline__ unsigned short f2bf(float f) {
  unsigned int u = __float_as_uint(f);
  u += 0x7fffu + ((u >> 16) & 1u);
  return (unsigned short)(u >> 16);
}

__device__ __forceinline__ unsigned stage_addr(int r, int c) {
  return (unsigned)(r * 64 + (((c + r + (r >> 2)) & 3) << 4));
}

__device__ __forceinline__ float sigmoidf_fast(float x) {
  return 1.f / (1.f + __expf(-x));
}
__device__ __forceinline__ float tanhf_fast(float x) {
  float a = fabsf(x);
  float e = __expf(-2.f * a);
  float t = (1.f - e) / (1.f + e);
  return copysignf(t, x);
}

// async 16B global->LDS. LDS dest must be wave-uniform base; lane lands at
// base + lane*16.
__device__ __forceinline__ void gload_lds16(const void* g, const char* lds) {
  __builtin_amdgcn_global_load_lds(
      (const __attribute__((address_space(1))) void*)(uintptr_t)g,
      (__attribute__((address_space(3))) void*)(uint32_t)(uintptr_t)lds, 16, 0, 0);
}

// ---------------- prologue ----------------
// grid 8833: [0,8192) pack_x (4 float4/thread); [8192,8704) pack_u; [8704,8832) init; 8832 zpg
__global__ void prologue_kernel(const float* __restrict__ x, const float* __restrict__ W,
                                const float* __restrict__ V,
                                const float* __restrict__ b0, const float* __restrict__ b1,
                                const float* __restrict__ b2,
                                unsigned short* __restrict__ xb, unsigned short* __restrict__ U,
                                float* __restrict__ q0, float* __restrict__ q1,
                                float* __restrict__ out, uint4* __restrict__ zpg) {
  __shared__ float T[64 * 65];
  const int bx = blockIdx.x;
  if (bx < 8192) {
    int base = bx * 1024 + threadIdx.x;
#pragma unroll
    for (int i = 0; i < 4; ++i) {
      int gid = base + i * 256;
      float4 v = ((const float4*)x)[gid];
      ushort4 o;
      o.x = f2bf(v.x); o.y = f2bf(v.y); o.z = f2bf(v.z); o.w = f2bf(v.w);
      ((ushort4*)xb)[gid] = o;
    }
  } else if (bx < 8704) {
    const int u = bx - 8192;
    const int j0 = (u & 31) * 64;
    const int k0 = (u >> 5) * 64;
    const int jl = threadIdx.x & 63;
    const int q  = threadIdx.x >> 6;
    const float* src = (k0 < 512) ? (W + (size_t)k0 * 3072) : (V + (size_t)(k0 - 512) * 3072);
#pragma unroll 4
    for (int i = 0; i < 16; ++i) {
      int kl = q * 16 + i;
      T[kl * 65 + jl] = src[(size_t)kl * 3072 + j0 + jl];
    }
    __syncthreads();
    const int kl = threadIdx.x & 63;
#pragma unroll 4
    for (int i = 0; i < 16; ++i) {
      int jj = q * 16 + i;
      U[(size_t)(j0 + jj) * 1024 + k0 + kl] = f2bf(T[kl * 65 + jj]);
    }
  } else if (bx < 8832) {
    int gid = (bx - 8704) * 256 + threadIdx.x;   // 32768
    q0[gid] = b0[gid & 1023];
    q1[gid] = b1[gid & 1023];
    if (gid < 4096) out[gid] = b2[gid & 127];
  } else {
    zpg[threadIdx.x] = make_uint4(0u, 0u, 0u, 0u);   // 4 KB zeros
  }
}

// ---------------- main (bf16): r0 structure + gload_lds staging ----------------
// grid (16 dt, 16 cj, 32 b) natural (r0 dispatch), block 256 (2x2 waves 64x64)
// per wave: acc[4][4] f32x4 (64 AGPR). A stage: 129 rows x 64B (row r =
// timestep s0-1+r). U stage: 256 rows (row = half*128 + col). Layout via
// stage_addr (r0-identical).
__global__ __launch_bounds__(256, 3) void qrnn_hyb(
    const unsigned short* __restrict__ wsb, const float* __restrict__ Vb,
    float* __restrict__ Fagg, float* __restrict__ Zagg) {
  __shared__ __align__(16) char smem[2 * SLOT_STRIDE];   // 49280 B

  const int dt = blockIdx.x;
  const int cj = blockIdx.y;
  const int b  = blockIdx.z;
  const int tid = threadIdx.x;
  const int lane = tid & 63;
  const int wid  = tid >> 6;
  const int wm = wid >> 1, wn = wid & 1;
  const int s0 = cj * 128;
  const int l15 = lane & 15, lc = lane >> 4;

  f32x4 acc[4][4];
#pragma unroll
  for (int i = 0; i < 4; ++i)
#pragma unroll
    for (int j = 0; j < 4; ++j) acc[i][j] = f32x4{0.f, 0.f, 0.f, 0.f};

  // ---- staging source offsets (bf16 elems rel. wsb; stage adds s*32) ----
  // gload writes phys chunk pc = wbase + lane linearly; phys slot p = pc&3 of
  // row r = pc>>2 must hold logical chunk q = (p - r - (r>>2)) & 3 so that
  // the stage_addr-based reads see r0's layout.
  unsigned vA[2], vA2, vU[4];
#pragma unroll
  for (int i = 0; i < 2; ++i) {
    int pc = wid * 128 + i * 64 + lane;       // 0..511
    int r = pc >> 2;                          // row 0..127
    int q = ((pc & 3) - r - (r >> 2)) & 3;
    int sg = s0 - 1 + r;
    vA[i] = (sg < 0) ? (ZERO_OFF_E + (unsigned)(q * 8))
                     : (XB_OFF_E + (unsigned)(b * 2048 + sg) * 512u + (unsigned)(q * 8));
  }
  // tail row 128 (chunks 512..515): p = lane, r=128, (r + (r>>2)) % 4 == 0 -> q = lane
  vA2 = XB_OFF_E + (unsigned)(b * 2048 + s0 + 127) * 512u + (unsigned)((lane & 3) * 8);
#pragma unroll
  for (int k = 0; k < 4; ++k) {
    int pc = wid * 256 + k * 64 + lane;       // 0..1023
    int r = pc >> 2;                          // row 0..255
    int col = r & 127, half = r >> 7;
    int j = (col < 64) ? (dt * 64 + col) : (1024 + dt * 64 + (col - 64));
    int q = ((pc & 3) - r - (r >> 2)) & 3;
    vU[k] = (unsigned)(j * 1024 + half * 512 + q * 8);
  }

  // ---- fragment read offsets (r0 verbatim; U base = 8256) ----
  unsigned roA[2][4], roU[2][4];
#pragma unroll
  for (int h2 = 0; h2 < 2; ++h2) {
#pragma unroll
    for (int mt = 0; mt < 4; ++mt) {
      int rr = wm * 64 + l15 + mt * 16 + 1 - h2;   // +1-h2: W reads x[t], V reads x[t-1]
      roA[h2][mt] = stage_addr(rr, lc);
    }
#pragma unroll
    for (int nt = 0; nt < 4; ++nt) {
      int rrU = h2 * 128 + wn * 64 + l15 + nt * 16;
      roU[h2][nt] = U_BASE + stage_addr(rrU, lc);
    }
  }

  auto stage = [&](int s, int slot) {
    const unsigned short* cur = wsb + s * 32;
    const unsigned sb = (unsigned)(slot * SLOT_STRIDE);
#pragma unroll
    for (int i = 0; i < 2; ++i) {
      unsigned d = (unsigned)__builtin_amdgcn_readfirstlane(
          (int)(sb + (unsigned)((wid * 128 + i * 64) * 16)));
      gload_lds16(cur + vA[i], smem + d);
    }
    {
      unsigned d2 = (unsigned)__builtin_amdgcn_readfirstlane((int)(sb + 8192u));
      if (lane < 4) gload_lds16(cur + vA2, smem + d2);   // all 4 waves: uniform vmcnt
    }
#pragma unroll
    for (int k = 0; k < 4; ++k) {
      unsigned d = (unsigned)__builtin_amdgcn_readfirstlane(
          (int)(sb + (unsigned)(U_BASE + (wid * 256 + k * 64) * 16)));
      gload_lds16(cur + vU[k], smem + d);
    }
  };

  stage(0, 0);

  // One stage: [vmcnt(0); barrier; stage(s+1 -> other slot); dual-pass h2:
  // {4 bfr reads; setprio(1); per-mt {1 afr read; 4 MFMA}; setprio(0)}].
  // Ring-2 safe: the other slot's readers (stage s-1) finished their ds_reads
  // before reaching this barrier; new gloads land by next stage's vmcnt(0).
#define SSTEP(S, SLOT, LAST)                                                           \
  {                                                                                    \
    asm volatile("s_waitcnt vmcnt(0)" ::: "memory");                                   \
    __builtin_amdgcn_s_barrier();                                                      \
    if (!(LAST)) stage((S) + 1, (SLOT) ^ 1);                                           \
    const char* buf = smem + (SLOT) * SLOT_STRIDE;                                     \
    _Pragma("unroll")                                                                  \
    for (int h2 = 0; h2 < 2; ++h2) {                                                   \
      short8 bfr[4];                                                                   \
      _Pragma("unroll")                                                                \
      for (int nt = 0; nt < 4; ++nt)                                                   \
        bfr[nt] = *(const short8*)(buf + roU[h2][nt]);                                 \
      __builtin_amdgcn_s_setprio(1);                                                   \
      _Pragma("unroll")                                                                \
      for (int mt = 0; mt < 4; ++mt) {                                                 \
        short8 afr = *(const short8*)(buf + roA[h2][mt]);                              \
        _Pragma("unroll")                                                              \
        for (int nt = 0; nt < 4; ++nt)                                                 \
          acc[mt][nt] = __builtin_amdgcn_mfma_f32_16x16x32_bf16(afr, bfr[nt],          \
                                                                acc[mt][nt], 0, 0, 0); \
      }                                                                                \
      __builtin_amdgcn_s_setprio(0);                                                   \
    }                                                                                  \
  }

#pragma unroll 1
  for (int s2 = 0; s2 < 16; s2 += 2) {
    SSTEP(s2,     0, false);
    SSTEP(s2 + 1, 1, (s2 + 1) == 15);
  }
#undef SSTEP

  // ---- fused activations + scan (r0 epilogue verbatim; 2 phases x 64 t) ----
  float* fA   = (float*)smem;            // [64][68]
  float* tzA  = (float*)(smem + 17408);  // [64][68]
  float* segF = (float*)(smem + 34816);  // [4][64]
  float* segZ = (float*)(smem + 35840);  // [4][64]

  const int d = tid & 63;
  float vb[4];
#pragma unroll
  for (int nt = 0; nt < 4; ++nt)
    vb[nt] = Vb[wn * 1024 + dt * 64 + nt * 16 + l15];

  float F_run = 1.f, Z_run = 0.f;

  for (int ph = 0; ph < 2; ++ph) {
    __syncthreads();
    if (wm == ph) {
      float* dst = (wn == 0) ? fA : tzA;
#pragma unroll
      for (int mt = 0; mt < 4; ++mt)
#pragma unroll
        for (int nt = 0; nt < 4; ++nt)
#pragma unroll
          for (int rg = 0; rg < 4; ++rg) {
            int t = mt * 16 + (lc << 2) + rg;   // phase-local 0..63
            int c = nt * 16 + l15;
            float v = acc[mt][nt][rg] + vb[nt];
            v = (wn == 0) ? sigmoidf_fast(v) : tanhf_fast(v);
            dst[t * 68 + c] = v;
          }
    }
    __syncthreads();
    {
      int seg = tid >> 6;
      float F = 1.f, Z = 0.f;
#pragma unroll 4
      for (int i = 0; i < 16; ++i) {
        int t = seg * 16 + i;
        float f  = fA[t * 68 + d];
        float tz = tzA[t * 68 + d];
        float z = (1.f - f) * tz;
        Z = f * Z + z;
        F *= f;
      }
      segF[seg * 64 + d] = F;
      segZ[seg * 64 + d] = Z;
    }
    __syncthreads();
    if (tid < 64) {
#pragma unroll
      for (int sgi = 0; sgi < 4; ++sgi) {
        float Fs = segF[sgi * 64 + tid], Zs = segZ[sgi * 64 + tid];
        Z_run = Fs * Z_run + Zs;
        F_run *= Fs;
      }
    }
  }
  if (tid < 64) {
    size_t o = (((size_t)b * 16 + cj) << 10) + dt * 64 + tid;
    Fagg[o] = F_run;
    Zagg[o] = Z_run;
  }
}

// ---------------- fallback (f32 path, 16-chunk layout) — previous verified kernel ----------------
template <bool USE_BF>
__global__ __launch_bounds__(256, 3) void qrnn_main(
    const unsigned short* __restrict__ wsb, const float* __restrict__ xf,
    const float* __restrict__ Vb,
    float* __restrict__ Fagg, float* __restrict__ Zagg) {
  __shared__ __align__(16) char smem[36864];

  const int dt = blockIdx.x;
  const int cj = blockIdx.y;
  const int b  = blockIdx.z;
  const int tid = threadIdx.x;
  const int lane = tid & 63;
  const int wid  = tid >> 6;
  const int wm = wid >> 1, wn = wid & 1;
  const int s0 = cj * 128;
  const int l15 = lane & 15, lc = lane >> 4;

  f32x4 acc[4][4];
#pragma unroll
  for (int i = 0; i < 4; ++i)
#pragma unroll
    for (int j = 0; j < 4; ++j) acc[i][j] = f32x4{0.f, 0.f, 0.f, 0.f};

  unsigned voffA[2];
  size_t offAF[2]; int zAF[2];
#pragma unroll
  for (int p = 0; p < 2; ++p) {
    int cw = tid + p * 256;
    int r = cw >> 2, c = cw & 3;
    int sg = s0 - 1 + r;
    voffA[p] = (sg < 0) ? (ZERO_OFF_E + (unsigned)(c * 8))
                        : (XB_OFF_E + (unsigned)(b * 2048 + sg) * 512u + (unsigned)(c * 8));
    zAF[p] = (sg < 0);
    offAF[p] = ((size_t)(b * 2048 + (sg < 0 ? 0 : sg)) << 9) + c * 8;
  }
  unsigned voffA3 = XB_OFF_E + (unsigned)(b * 2048 + s0 + 127) * 512u + (unsigned)((tid & 3) * 8);
  size_t offAF3 = ((size_t)(b * 2048 + s0 + 127) << 9) + (tid & 3) * 8;

  unsigned voffU[4];
#pragma unroll
  for (int k = 0; k < 4; ++k) {
    int uw = tid + k * 256;
    int r = uw >> 2, c = uw & 3;
    int col = r & 127, half = r >> 7;
    int j = (col < 64) ? (dt * 64 + col) : (1024 + dt * 64 + (col - 64));
    voffU[k] = (unsigned)(j * 1024 + half * 512 + c * 8);
  }

  unsigned wA[2], wU[4];
#pragma unroll
  for (int p = 0; p < 2; ++p) {
    int cw = tid + p * 256;
    wA[p] = stage_addr(cw >> 2, cw & 3);
  }
  const unsigned wA3 = stage_addr(128, tid & 3);
#pragma unroll
  for (int k = 0; k < 4; ++k) {
    int uw = tid + k * 256;
    wU[k] = U_BASE + stage_addr(uw >> 2, uw & 3);
  }

  unsigned roA[2][4], roU[2][4];
#pragma unroll
  for (int h2 = 0; h2 < 2; ++h2) {
#pragma unroll
    for (int mt = 0; mt < 4; ++mt) {
      int rr = wm * 64 + l15 + mt * 16 + 1 - h2;
      roA[h2][mt] = stage_addr(rr, lc);
    }
#pragma unroll
    for (int nt = 0; nt < 4; ++nt) {
      int rrU = h2 * 128 + wn * 64 + l15 + nt * 16;
      roU[h2][nt] = U_BASE + stage_addr(rrU, lc);
    }
  }

  uint4 pA0, pA1, pA3, pU0, pU1, pU2, pU3;

  auto load_stage = [&](int s) {
    const unsigned short* cur = wsb + s * 32;
    if constexpr (USE_BF) {
      pA0 = *(const uint4*)(cur + voffA[0]);
      pA1 = *(const uint4*)(cur + voffA[1]);
      if (tid < 4) pA3 = *(const uint4*)(cur + voffA3);
    } else {
      const float* curf = xf + s * 32;
#pragma unroll
      for (int p = 0; p < 2; ++p) {
        uint4 v = make_uint4(0u, 0u, 0u, 0u);
        if (!zAF[p]) {
          float4 a0 = *(const float4*)(curf + offAF[p]);
          float4 a1 = *(const float4*)(curf + offAF[p] + 4);
          v.x = (unsigned)f2bf(a0.x) | ((unsigned)f2bf(a0.y) << 16);
          v.y = (unsigned)f2bf(a0.z) | ((unsigned)f2bf(a0.w) << 16);
          v.z = (unsigned)f2bf(a1.x) | ((unsigned)f2bf(a1.y) << 16);
          v.w = (unsigned)f2bf(a1.z) | ((unsigned)f2bf(a1.w) << 16);
        }
        if (p == 0) pA0 = v; else pA1 = v;
      }
      if (tid < 4) {
        float4 a0 = *(const float4*)(curf + offAF3);
        float4 a1 = *(const float4*)(curf + offAF3 + 4);
        pA3.x = (unsigned)f2bf(a0.x) | ((unsigned)f2bf(a0.y) << 16);
        pA3.y = (unsigned)f2bf(a0.z) | ((unsigned)f2bf(a0.w) << 16);
        pA3.z = (unsigned)f2bf(a1.x) | ((unsigned)f2bf(a1.y) << 16);
        pA3.w = (unsigned)f2bf(a1.z) | ((unsigned)f2bf(a1.w) << 16);
      }
    }
    pU0 = *(const uint4*)(cur + voffU[0]);
    pU1 = *(const uint4*)(cur + voffU[1]);
    pU2 = *(const uint4*)(cur + voffU[2]);
    pU3 = *(const uint4*)(cur + voffU[3]);
  };

  load_stage(0);

#pragma unroll 1
  for (int s = 0; s < 16; ++s) {
    __syncthreads();
    *(uint4*)(smem + wA[0]) = pA0;
    *(uint4*)(smem + wA[1]) = pA1;
    if (tid < 4) *(uint4*)(smem + wA3) = pA3;
    *(uint4*)(smem + wU[0]) = pU0;
    *(uint4*)(smem + wU[1]) = pU1;
    *(uint4*)(smem + wU[2]) = pU2;
    *(uint4*)(smem + wU[3]) = pU3;
    __syncthreads();
    if (s < 15) load_stage(s + 1);
#pragma unroll
    for (int h2 = 0; h2 < 2; ++h2) {
      short8 bfr[4];
#pragma unroll
      for (int nt = 0; nt < 4; ++nt)
        bfr[nt] = *(const short8*)(smem + roU[h2][nt]);
#pragma unroll
      for (int mt = 0; mt < 4; ++mt) {
        short8 afr = *(const short8*)(smem + roA[h2][mt]);
#pragma unroll
        for (int nt = 0; nt < 4; ++nt)
          acc[mt][nt] = __builtin_amdgcn_mfma_f32_16x16x32_bf16(afr, bfr[nt], acc[mt][nt], 0, 0, 0);
      }
    }
  }

  float* fA   = (float*)smem;
  float* tzA  = (float*)(smem + 17408);
  float* segF = (float*)(smem + 34816);
  float* segZ = (float*)(smem + 35840);

  const int d = tid & 63;
  float vb[4];
#pragma unroll
  for (int nt = 0; nt < 4; ++nt)
    vb[nt] = Vb[wn * 1024 + dt * 64 + nt * 16 + l15];

  float F_run = 1.f, Z_run = 0.f;

  for (int ph = 0; ph < 2; ++ph) {
    __syncthreads();
    if (wm == ph) {
      float* dst = (wn == 0) ? fA : tzA;
#pragma unroll
      for (int mt = 0; mt < 4; ++mt)
#pragma unroll
        for (int nt = 0; nt < 4; ++nt)
#pragma unroll
          for (int rg = 0; rg < 4; ++rg) {
            int t = mt * 16 + ((lane >> 4) << 2) + rg;
            int c = nt * 16 + l15;
            float v = acc[mt][nt][rg] + vb[nt];
            v = (wn == 0) ? sigmoidf_fast(v) : tanhf_fast(v);
            dst[t * 68 + c] = v;
          }
    }
    __syncthreads();
    {
      int seg = tid >> 6;
      float F = 1.f, Z = 0.f;
#pragma unroll 4
      for (int i = 0; i < 16; ++i) {
        int t = seg * 16 + i;
        float f  = fA[t * 68 + d];
        float tz = tzA[t * 68 + d];
        float z = (1.f - f) * tz;
        Z = f * Z + z;
        F *= f;
      }
      segF[seg * 64 + d] = F;
      segZ[seg * 64 + d] = Z;
    }
    __syncthreads();
    if (tid < 64) {
#pragma unroll
      for (int sgi = 0; sgi < 4; ++sgi) {
        float Fs = segF[sgi * 64 + tid], Zs = segZ[sgi * 64 + tid];
        Z_run = Fs * Z_run + Zs;
        F_run *= Fs;
      }
    }
  }
  if (tid < 64) {
    size_t o = (((size_t)b * 16 + cj) << 10) + dt * 64 + tid;
    Fagg[o] = F_run;
    Zagg[o] = Z_run;
  }
}

// ---------------- head: K-split o-gate + nch-chunk combine ----------------
// grid (16 dtile, 32 b), block 256 = 64 d x 4 k-segments
__global__ void head_kernel(const float* __restrict__ x, const float* __restrict__ W,
                            const float* __restrict__ V, const float* __restrict__ Vb,
                            const float* __restrict__ Fagg, const float* __restrict__ Zagg,
                            float* __restrict__ h, int nch) {
  __shared__ float red[4][64];
  const int dl = threadIdx.x & 63;
  const int w  = threadIdx.x >> 6;
  const int d = blockIdx.x * 64 + dl;
  const int b = blockIdx.y;

  const float* xl = x + ((size_t)b * 2048 + 2047) * 512;
  const float* xp = xl - 512;
  const float* Wc = W + 2048 + d;
  const float* Vc = V + 2048 + d;
  float po = 0.f;
  const int k0 = w * 128;
#pragma unroll 8
  for (int k = k0; k < k0 + 128; ++k) {
    po += xl[k] * Wc[(size_t)k * 3072];
    po += xp[k] * Vc[(size_t)k * 3072];
  }
  red[w][dl] = po;
  __syncthreads();
  if (w == 0) {
    po = red[0][dl] + red[1][dl] + red[2][dl] + red[3][dl] + Vb[2048 + d];
    float c = 0.f;
    for (int j = 0; j < nch; ++j) {
      size_t o = (((size_t)b * nch + j) << 10) + d;
      c = Fagg[o] * c + Zagg[o];
    }
    h[((size_t)b << 10) + d] = c * sigmoidf_fast(po);
  }
}

// ---------------- MLP: K-split atomic GEMV (ReLU on input) ----------------
// grid (N/64, B, 4 ksplit), block 256 = 64 n x 4 waves
__global__ void mlp_atomic_kernel(const float* __restrict__ in, const float* __restrict__ Wt,
                                  float* __restrict__ out, int K, int N, int relu_in) {
  __shared__ float red[4][64];
  const int nl = threadIdx.x & 63;
  const int w  = threadIdx.x >> 6;
  const int n = blockIdx.x * 64 + nl;
  const int b = blockIdx.y;
  const int k0 = blockIdx.z * (K >> 2) + w * (K >> 4);
  const float* row = in + (size_t)b * K;
  const float* Wc = Wt + n;
  float s = 0.f;
#pragma unroll 8
  for (int k = k0; k < k0 + (K >> 4); ++k) {
    float v = row[k];
    if (relu_in) v = fmaxf(v, 0.f);
    s += v * Wc[(size_t)k * N];
  }
  red[w][nl] = s;
  __syncthreads();
  if (w == 0) {
    s = red[0][nl] + red[1][nl] + red[2][nl] + red[3][nl];
    atomicAdd(&out[(size_t)b * N + n], s);
  }
}

extern "C" void kernel_launch(void* const* d_in, const int* in_sizes, int n_in,
                              void* d_out, int out_size, void* d_ws, size_t ws_size,
                              hipStream_t stream) {
  const float* x  = (const float*)d_in[0];
  const float* W  = (const float*)d_in[1];
  const float* V  = (const float*)d_in[2];
  const float* Vb = (const float*)d_in[3];
  const float* W0 = (const float*)d_in[4];
  const float* b0 = (const float*)d_in[5];
  const float* W1 = (const float*)d_in[6];
  const float* b1 = (const float*)d_in[7];
  const float* W2 = (const float*)d_in[8];
  const float* b2 = (const float*)d_in[9];

  char* ws = (char*)d_ws;
  unsigned short* U = (unsigned short*)(ws);                              // 4 MiB
  float* Fagg = (float*)(ws + (size_t)4 * 1024 * 1024);                   // 2 MiB
  float* Zagg = (float*)(ws + (size_t)6 * 1024 * 1024);                   // 2 MiB
  float* h    = (float*)(ws + (size_t)8 * 1024 * 1024);                   // 128 KiB
  float* q0   = (float*)(ws + (size_t)8 * 1024 * 1024 + 256 * 1024);
  float* q1   = (float*)(ws + (size_t)8 * 1024 * 1024 + 512 * 1024);
  uint4* zpg  = (uint4*)(ws + (size_t)12 * 1024 * 1024);                  // 4 KiB zeros
  unsigned short* xb = (unsigned short*)(ws + (size_t)16 * 1024 * 1024);  // 64 MiB

  const size_t need_bf = (size_t)16 * 1024 * 1024 + (size_t)67108864;
  int use_bf = (ws_size >= need_bf) ? 1 : 0;   // constant across calls -> graph-safe

  prologue_kernel<<<8833, 256, 0, stream>>>(x, W, V, b0, b1, b2, xb, U, q0, q1,
                                            (float*)d_out, zpg);
  if (use_bf) {
    qrnn_hyb<<<dim3(16, 16, 32), 256, 0, stream>>>((const unsigned short*)ws, Vb, Fagg, Zagg);
  } else {
    qrnn_main<false><<<dim3(16, 16, 32), 256, 0, stream>>>((const unsigned short*)ws, x,
                                                           Vb, Fagg, Zagg);
  }
  head_kernel<<<dim3(16, 32), 256, 0, stream>>>(x, W, V, Vb, Fagg, Zagg, h, 16);
  mlp_atomic_kernel<<<dim3(16, 32, 4), 256, 0, stream>>>(h, W0, q0, 1024, 1024, 0);
  mlp_atomic_kernel<<<dim3(16, 32, 4), 256, 0, stream>>>(q0, W1, q1, 1024, 1024, 1);
  mlp_atomic_kernel<<<dim3(2, 32, 4), 256, 0, stream>>>(q1, W2, (float*)d_out, 1024, 128, 1);
}